// Round 1
// baseline (49.876 us; speedup 1.0000x reference)
//
#include <hip/hip_runtime.h>
#include <math.h>

// Sizes (compile-time constants from the reference)
#define N_A 64
#define N_B 128
#define N_C 128
#define D_IN 256
#define D_H 32
#define NHEADS 4
#define DMODEL (D_H * NHEADS)   // 128

// Workspace layout (float offsets)
#define OFF_Q    0                      // 64*128
#define OFF_KB   (OFF_Q   + N_A*DMODEL)     // 8192
#define OFF_KC   (OFF_KB  + N_B*DMODEL)
#define OFF_VB   (OFF_KC  + N_C*DMODEL)
#define OFF_VC   (OFF_VB  + N_B*DMODEL)
#define OFF_SAB  (OFF_VC  + N_C*DMODEL)     // 64*4*128
#define OFF_SAC  (OFF_SAB + N_A*NHEADS*N_B)
#define OFF_SBC  (OFF_SAC + N_A*NHEADS*N_C) // 4*128*128
#define OFF_PB   (OFF_SBC + NHEADS*N_B*N_C) // 128*4*4
#define OFF_PC   (OFF_PB  + N_B*NHEADS*4)
#define OFF_M    (OFF_PC  + N_C*NHEADS*4)   // 64*4
#define OFF_Z    (OFF_M   + N_A*NHEADS)

#define SCALE 0.17677669529663687f  // 1/sqrt(32)

// ---------------- Kernel 1: projections Q, Kb, Kc, Vb, Vc ----------------
// One block (128 threads) per output row; dot over D_IN=256 with X-row in LDS.
__global__ __launch_bounds__(128) void proj_kernel(
    const float* __restrict__ Ha, const float* __restrict__ Hb,
    const float* __restrict__ Hc, const float* __restrict__ Wq,
    const float* __restrict__ Wk, const float* __restrict__ Wv,
    float* __restrict__ ws) {
  int row = blockIdx.x;                 // 0..575
  const float* X; const float* W; float* Y; int r;
  if (row < 64)        { X = Ha; W = Wq; Y = ws + OFF_Q;  r = row; }
  else if (row < 192)  { X = Hb; W = Wk; Y = ws + OFF_KB; r = row - 64; }
  else if (row < 320)  { X = Hc; W = Wk; Y = ws + OFF_KC; r = row - 192; }
  else if (row < 448)  { X = Hb; W = Wv; Y = ws + OFF_VB; r = row - 320; }
  else                 { X = Hc; W = Wv; Y = ws + OFF_VC; r = row - 448; }

  __shared__ float xs[D_IN];
  int t = threadIdx.x;                  // 0..127
  xs[t]       = X[r * D_IN + t];
  xs[t + 128] = X[r * D_IN + t + 128];
  __syncthreads();

  float acc = 0.0f;
  #pragma unroll 8
  for (int i = 0; i < D_IN; ++i) acc = fmaf(xs[i], W[i * DMODEL + t], acc);
  Y[r * DMODEL + t] = acc;
}

// ---------------- Kernel 2: s_ab, s_ac, s_bc (pre-scaled), pb, pc --------
// Flat thread per output element.
// Regions: sab [0,32768) sac [32768,65536) sbc [65536,131072)
//          pb [131072,133120) pc [133120,135168)
__global__ __launch_bounds__(256) void scores_kernel(
    const float* __restrict__ ws_in, const float* __restrict__ fcw,
    float* __restrict__ ws) {
  const float* Q  = ws_in + OFF_Q;
  const float* Kb = ws_in + OFF_KB;
  const float* Kc = ws_in + OFF_KC;
  const float* Vb = ws_in + OFF_VB;
  const float* Vc = ws_in + OFF_VC;

  int idx = blockIdx.x * 256 + threadIdx.x;
  if (idx < 32768) {
    // sab[(a*4+h)*128 + b] = scale * Q[a,h,:]·Kb[b,h,:]
    int b = idx & 127; int ah = idx >> 7; int a = ah >> 2; int h = ah & 3;
    const float* q = Q  + a * DMODEL + h * D_H;
    const float* k = Kb + b * DMODEL + h * D_H;
    float acc = 0.0f;
    #pragma unroll
    for (int d = 0; d < D_H; ++d) acc = fmaf(q[d], k[d], acc);
    ws[OFF_SAB + idx] = acc * SCALE;
  } else if (idx < 65536) {
    int j = idx - 32768;
    int c = j & 127; int ah = j >> 7; int a = ah >> 2; int h = ah & 3;
    const float* q = Q  + a * DMODEL + h * D_H;
    const float* k = Kc + c * DMODEL + h * D_H;
    float acc = 0.0f;
    #pragma unroll
    for (int d = 0; d < D_H; ++d) acc = fmaf(q[d], k[d], acc);
    ws[OFF_SAC + j] = acc * SCALE;
  } else if (idx < 131072) {
    int j = idx - 65536;                 // (h*128+b)*128 + c
    int c = j & 127; int hb = j >> 7; int h = hb >> 7; int b = hb & 127;
    const float* kb = Kb + b * DMODEL + h * D_H;
    const float* kc = Kc + c * DMODEL + h * D_H;
    float acc = 0.0f;
    #pragma unroll
    for (int d = 0; d < D_H; ++d) acc = fmaf(kb[d], kc[d], acc);
    ws[OFF_SBC + j] = acc * SCALE;
  } else if (idx < 133120) {
    int j = idx - 131072;                // pb[(b*4+h)*4+kk]
    int kk = j & 3; int h = (j >> 2) & 3; int b = j >> 4;
    const float* v = Vb + b * DMODEL + h * D_H;
    const float* w = fcw + kk * D_H;
    float acc = 0.0f;
    #pragma unroll
    for (int d = 0; d < D_H; ++d) acc = fmaf(v[d], w[d], acc);
    ws[OFF_PB + j] = acc;
  } else if (idx < 135168) {
    int j = idx - 133120;                // pc[(c*4+h)*4+kk]
    int kk = j & 3; int h = (j >> 2) & 3; int c = j >> 4;
    const float* v = Vc + c * DMODEL + h * D_H;
    const float* w = fcw + kk * D_H;
    float acc = 0.0f;
    #pragma unroll
    for (int d = 0; d < D_H; ++d) acc = fmaf(v[d], w[d], acc);
    ws[OFF_PC + j] = acc;
  }
}

// ---------------- Kernel 3: softmax stats m, Z per (a,h) -----------------
// One block (256 threads) per (a,h); two passes over the 16384 (b,c) plane.
__global__ __launch_bounds__(256) void softmax_stats_kernel(
    const float* __restrict__ ws_in, float* __restrict__ ws) {
  int ah = blockIdx.x;                  // 0..255
  int h = ah & 3;
  const float* pab = ws_in + OFF_SAB + ah * N_B;
  const float* pac = ws_in + OFF_SAC + ah * N_C;
  const float* pbc = ws_in + OFF_SBC + h * N_B * N_C;
  int t = threadIdx.x;

  float mx = -1e30f;
  for (int i = t; i < N_B * N_C; i += 256) {
    int b = i >> 7; int c = i & 127;
    float s = pab[b] + pac[c] + pbc[i];
    mx = fmaxf(mx, s);
  }
  __shared__ float redm[4];
  #pragma unroll
  for (int o = 32; o > 0; o >>= 1) mx = fmaxf(mx, __shfl_down(mx, o, 64));
  if ((t & 63) == 0) redm[t >> 6] = mx;
  __syncthreads();
  float mall = fmaxf(fmaxf(redm[0], redm[1]), fmaxf(redm[2], redm[3]));

  float sum = 0.0f;
  for (int i = t; i < N_B * N_C; i += 256) {
    int b = i >> 7; int c = i & 127;
    float s = pab[b] + pac[c] + pbc[i];
    sum += expf(s - mall);
  }
  __shared__ float redz[4];
  #pragma unroll
  for (int o = 32; o > 0; o >>= 1) sum += __shfl_down(sum, o, 64);
  if ((t & 63) == 0) redz[t >> 6] = sum;
  __syncthreads();
  if (t == 0) {
    ws[OFF_M + ah] = mall;
    ws[OFF_Z + ah] = redz[0] + redz[1] + redz[2] + redz[3];
  }
}

// ---------------- Kernel 4: fused output -----------------
// out[a,b,c] = sigmoid( sum_kk alpha[a,h,bb,cc]*(pb[bb,h,kk]+pc[cc,h,kk]) + fc_b )
// with h = b>>5, bb = ((b&31)<<2)|(c>>5), cc = ((c&31)<<2)|kk.
__global__ __launch_bounds__(256) void out_kernel(
    const float* __restrict__ ws, const float* __restrict__ fcb,
    float* __restrict__ out) {
  int idx = blockIdx.x * 256 + threadIdx.x;     // < 64*128*128
  int a = idx >> 14;
  int rem = idx & 16383;
  int b = rem >> 7;
  int c = rem & 127;

  int h  = b >> 5;
  int bb = ((b & 31) << 2) | (c >> 5);
  int ah = a * 4 + h;

  float sabv = ws[OFF_SAB + ah * N_B + bb];
  float mv   = ws[OFF_M + ah];
  float zinv = 1.0f / ws[OFF_Z + ah];
  const float* pacRow = ws + OFF_SAC + ah * N_C;
  const float* pbcRow = ws + OFF_SBC + (h * N_B + bb) * N_C;
  const float* pbRow  = ws + OFF_PB + (bb * 4 + h) * 4;

  float acc = 0.0f;
  #pragma unroll
  for (int kk = 0; kk < 4; ++kk) {
    int cc = ((c & 31) << 2) | kk;
    float s = sabv + pacRow[cc] + pbcRow[cc];
    float alpha = expf(s - mv) * zinv;
    float pv = pbRow[kk] + ws[OFF_PC + (cc * 4 + h) * 4 + kk];
    acc = fmaf(alpha, pv, acc);
  }
  float x = acc + fcb[0];
  out[idx] = 1.0f / (1.0f + expf(-x));
}

extern "C" void kernel_launch(void* const* d_in, const int* in_sizes, int n_in,
                              void* d_out, int out_size, void* d_ws, size_t ws_size,
                              hipStream_t stream) {
  const float* Ha  = (const float*)d_in[0];
  const float* Hb  = (const float*)d_in[1];
  const float* Hc  = (const float*)d_in[2];
  const float* Wq  = (const float*)d_in[3];
  const float* Wk  = (const float*)d_in[4];
  const float* Wv  = (const float*)d_in[5];
  const float* fcw = (const float*)d_in[6];
  const float* fcb = (const float*)d_in[7];
  float* out = (float*)d_out;
  float* ws  = (float*)d_ws;

  // K1: 576 rows (64 Q + 4*128 K/V), 128 threads each
  proj_kernel<<<576, 128, 0, stream>>>(Ha, Hb, Hc, Wq, Wk, Wv, ws);
  // K2: 135168 elems / 256
  scores_kernel<<<528, 256, 0, stream>>>(ws, fcw, ws);
  // K3: one block per (a,h)
  softmax_stats_kernel<<<256, 256, 0, stream>>>(ws, ws);
  // K4: 1,048,576 outputs / 256
  out_kernel<<<4096, 256, 0, stream>>>(ws, fcb, out);
}